// Round 7
// baseline (158.884 us; speedup 1.0000x reference)
//
#include <hip/hip_runtime.h>
#include <hip/hip_bf16.h>

#define TT 512
#define HH 1024
#define EE 32
#define KK 4
#define II 512
#define SS 2048

using f32x4 = __attribute__((ext_vector_type(4))) float;
using s16x8 = __attribute__((ext_vector_type(8))) short;
using u32x4 = __attribute__((ext_vector_type(4))) unsigned;

__device__ __forceinline__ unsigned short f2bf(float f){
  unsigned int u = __builtin_bit_cast(unsigned int, f);
  u += 0x7fffu + ((u >> 16) & 1u);
  return (unsigned short)(u >> 16);
}
__device__ __forceinline__ unsigned pk2(float a, float b){
  return (unsigned)f2bf(a) | ((unsigned)f2bf(b) << 16);
}

typedef __attribute__((address_space(1))) const unsigned GU;
typedef __attribute__((address_space(3))) unsigned LU;

__device__ __forceinline__ void gload16(const void* g, void* l){
  __builtin_amdgcn_global_load_lds((GU*)g, (LU*)l, 16, 0, 0);
}

// ---------------- router: logits, top-4, weights, sigmoid gate, x->bf16 -----
__global__ __launch_bounds__(64) void k_router(
    const float* __restrict__ x, const float* __restrict__ Wg,
    unsigned short* __restrict__ xb, int* __restrict__ topk_idx,
    float* __restrict__ topk_w, float* __restrict__ sig_gate){
  int t = blockIdx.x; int l = threadIdx.x;
  const float* xr = x + (size_t)t * HH;
  #pragma unroll
  for(int i=0;i<HH/64;i++){
    int h = l + 64*i;
    xb[(size_t)t*HH + h] = f2bf(xr[h]);
  }
  float acc0=0.f, acc1=0.f, acc2=0.f, acc3=0.f;
  if(l < EE+1){
    const float* wcol = Wg + l;
    for(int h=0; h<HH; h+=4){
      acc0 += xr[h]   * wcol[(size_t)h*(EE+1)];
      acc1 += xr[h+1] * wcol[(size_t)(h+1)*(EE+1)];
      acc2 += xr[h+2] * wcol[(size_t)(h+2)*(EE+1)];
      acc3 += xr[h+3] * wcol[(size_t)(h+3)*(EE+1)];
    }
  }
  __shared__ float lg[EE+1];
  if(l < EE+1) lg[l] = (acc0+acc1)+(acc2+acc3);
  __syncthreads();
  if(l == 0){
    float v[EE];
    #pragma unroll
    for(int i=0;i<EE;i++) v[i]=lg[i];
    int idx[KK]; float val[KK];
    #pragma unroll
    for(int k=0;k<KK;k++){
      float m=-1e30f; int mi=0;
      for(int i=0;i<EE;i++){ if(v[i]>m){ m=v[i]; mi=i; } }
      idx[k]=mi; val[k]=m; v[mi]=-1e30f;
    }
    float mx = val[0], s=0.f; float w[KK];
    #pragma unroll
    for(int k=0;k<KK;k++){ w[k]=__expf(val[k]-mx); s+=w[k]; }
    float inv = 1.f/s;
    #pragma unroll
    for(int k=0;k<KK;k++){ topk_idx[t*KK+k]=idx[k]; topk_w[t*KK+k]=w[k]*inv; }
    sig_gate[t] = 1.f/(1.f+__expf(-lg[EE]));
  }
}

// ---------------- per-expert token list (deterministic compaction) ----------
__global__ __launch_bounds__(64) void k_build(
    const int* __restrict__ topk_idx, const float* __restrict__ topk_w,
    int* __restrict__ token_list, float* __restrict__ weight_list,
    int* __restrict__ counts){
  int e = blockIdx.x; int l = threadIdx.x;
  int cnt = 0;
  for(int c=0;c<TT;c+=64){
    int t = c + l;
    int kk = -1;
    #pragma unroll
    for(int k=0;k<KK;k++) if(topk_idx[t*KK+k]==e) kk=k;
    unsigned long long b = __ballot(kk>=0);
    int pre = __popcll(b & ((1ull<<l)-1ull));
    if(kk>=0){
      token_list[e*TT + cnt + pre] = t;
      weight_list[e*TT + cnt + pre] = topk_w[t*KK+kk];
    }
    cnt += __popcll(b);
  }
  if(l==0) counts[e]=cnt;
}

// ============ core GEMM: C(64x64) += A(64xK) * B(Kx64), K-step 32 ===========
// Depth-3.5 pipeline: ISSUE(s+3) / COMPUTE(s) / PACK(s+1) / raw-barrier.
// A: global_load_lds DMA into 4-stage linear LDS ring [stage][64 rows][32 bf16],
//    source-seg swizzle seg_src = seg ^ ((row>>1)&3) -> conflict-free b128 reads.
// B: reg-staged 4-slot ring (2 float4/mat), packed bf16 to 2-buffer swizzled
//    dword LDS [buf][16 kp][64] (R6-verified layout, ~2-way).
// Compiler emits counted vmcnt before PACK (tracks B regs; in-order retire
// also guarantees the older A DMA has landed). Never vmcnt(0) in the loop.

#define ISSUE(S, SLOT) { \
    int sc_ = ((S) < NK) ? (S) : (NK-1); \
    gload16(Asrc + (size_t)sc_*32, Aw + (SLOT)*2048); \
    const float* p_ = Gp + (size_t)(sc_*32 + krow)*ldb; \
    bgs##SLOT##a = *reinterpret_cast<const float4*>(p_); \
    bgs##SLOT##b = *reinterpret_cast<const float4*>(p_ + ldb); \
    if(DUAL){ \
      const float* q_ = Up + (size_t)(sc_*32 + krow)*ldb; \
      bus##SLOT##a = *reinterpret_cast<const float4*>(q_); \
      bus##SLOT##b = *reinterpret_cast<const float4*>(q_ + ldb); \
    } }

#define PACKB(SLOT, PAR) { \
    u32x4 vg_; \
    vg_.x = pk2(bgs##SLOT##a.x, bgs##SLOT##b.x); \
    vg_.y = pk2(bgs##SLOT##a.y, bgs##SLOT##b.y); \
    vg_.z = pk2(bgs##SLOT##a.z, bgs##SLOT##b.z); \
    vg_.w = pk2(bgs##SLOT##a.w, bgs##SLOT##b.w); \
    *reinterpret_cast<u32x4*>(Bg + (PAR)*1024 + wB) = vg_; \
    if(DUAL){ u32x4 vu_; \
      vu_.x = pk2(bus##SLOT##a.x, bus##SLOT##b.x); \
      vu_.y = pk2(bus##SLOT##a.y, bus##SLOT##b.y); \
      vu_.z = pk2(bus##SLOT##a.z, bus##SLOT##b.z); \
      vu_.w = pk2(bus##SLOT##a.w, bus##SLOT##b.w); \
      *reinterpret_cast<u32x4*>(Bu + (PAR)*1024 + wB) = vu_; } }

#define COMPUTE(P) { \
    s16x8 af_ = *reinterpret_cast<const s16x8*>(Al + (P)*2048 + aRd); \
    const unsigned* Bgh_ = Bg + ((P)&1)*1024; \
    const unsigned* Buh_ = Bu + ((P)&1)*1024; \
    _Pragma("unroll") \
    for(int c=0;c<4;c++){ \
      int base_ = kt*256 + ((c*16+mm) ^ (int)swR); \
      u32x4 tg_; tg_.x=Bgh_[base_]; tg_.y=Bgh_[base_+64]; \
      tg_.z=Bgh_[base_+128]; tg_.w=Bgh_[base_+192]; \
      ag[c] = __builtin_amdgcn_mfma_f32_16x16x32_bf16(af_, __builtin_bit_cast(s16x8, tg_), ag[c], 0,0,0); \
      if(DUAL){ \
        u32x4 tu_; tu_.x=Buh_[base_]; tu_.y=Buh_[base_+64]; \
        tu_.z=Buh_[base_+128]; tu_.w=Buh_[base_+192]; \
        au[c] = __builtin_amdgcn_mfma_f32_16x16x32_bf16(af_, __builtin_bit_cast(s16x8, tu_), au[c], 0,0,0); } } }

#define BARR() { asm volatile("s_waitcnt lgkmcnt(0)" ::: "memory"); \
    __builtin_amdgcn_s_barrier(); \
    __builtin_amdgcn_sched_barrier(0); }

template<bool DUAL>
__device__ __forceinline__ void gemm64d(
    const unsigned short* __restrict__ Asrc,   // per-lane: rowptr + swz-seg*8
    const float* __restrict__ Gp, const float* __restrict__ Up,
    int ldb, int NK,
    f32x4* ag, f32x4* au,
    unsigned short* Al, unsigned* Bg, unsigned* Bu, int tid)
{
  const int w = tid>>6, l = tid&63;
  const int m16 = tid&15, g2 = tid>>4;
  const int krow = 2*g2;
  const int kt = l>>4, mm = l&15;
  const unsigned swW = ((unsigned)((g2>>2)&3))<<3;
  const int wB = g2*64 + ((4*m16) ^ (int)swW);
  const int arow = w*16 + mm;
  const int aRd = arow*32 + ((kt ^ ((arow>>1)&3))<<3);
  const unsigned swR = ((unsigned)(kt&3))<<3;
  unsigned short* Aw = Al + w*512;   // wave's DMA dest (16 rows x 32 bf16)

  float4 bgs0a,bgs0b,bgs1a,bgs1b,bgs2a,bgs2b,bgs3a,bgs3b;
  float4 bus0a,bus0b,bus1a,bus1b,bus2a,bus2b,bus3a,bus3b;

  ISSUE(0,0) ISSUE(1,1) ISSUE(2,2)
  PACKB(0,0)
  BARR()
  for(int ks=0; ks<NK; ks+=4){
    ISSUE(ks+3,3) COMPUTE(0) PACKB(1,1) BARR()
    ISSUE(ks+4,0) COMPUTE(1) PACKB(2,0) BARR()
    ISSUE(ks+5,1) COMPUTE(2) PACKB(3,1) BARR()
    ISSUE(ks+6,2) COMPUTE(3) PACKB(0,0) BARR()
  }
}

// ---------------- phase 2: ALL gate-up (shared + routed), 64x64 tiles -------
__global__ __launch_bounds__(256, 2) void k_gateup_all(
    const unsigned short* __restrict__ xb,
    const float* __restrict__ Wsg, const float* __restrict__ Wsu,
    unsigned short* __restrict__ Hs,
    const float* __restrict__ Wgate, const float* __restrict__ Wup,
    const int* __restrict__ token_list, const int* __restrict__ counts,
    unsigned short* __restrict__ hbuf){
  __shared__ __align__(16) unsigned short Albuf[4*64*32];  // 16 KB
  __shared__ __align__(16) unsigned Bgbuf[2*16*64];        // 8 KB
  __shared__ __align__(16) unsigned Bubuf[2*16*64];        // 8 KB
  int tid = threadIdx.x, w = tid>>6, l = tid&63;
  int m16 = tid&15;
  const int r_lds = w*16 + (l>>2);
  const int sseg  = (l&3) ^ ((r_lds>>1)&3);
  int bid = blockIdx.x;
  f32x4 zero = {0.f,0.f,0.f,0.f};
  const int NSH = (TT/64)*(SS/64);   // 256

  if(bid < NSH){
    int n0 = (bid & 31) * 64;
    int r0 = (bid >> 5) * 64;
    f32x4 ag[4]={zero,zero,zero,zero}, au[4]={zero,zero,zero,zero};
    const unsigned short* Asrc = xb + (size_t)(r0 + r_lds)*HH + sseg*8;
    const float* Gp = Wsg + n0 + 4*m16;
    const float* Up = Wsu + n0 + 4*m16;
    gemm64d<true>(Asrc, Gp, Up, SS, HH/32, ag, au, Albuf, Bgbuf, Bubuf, tid);
    int mm = l&15, rb = r0 + w*16 + (l>>4)*4;
    #pragma unroll
    for(int c=0;c<4;c++){
      #pragma unroll
      for(int j=0;j<4;j++){
        float g = ag[c][j], u = au[c][j];
        Hs[(size_t)(rb+j)*SS + n0 + c*16 + mm] = f2bf(g*u/(1.f+__expf(-g)));
      }
    }
  } else {
    int b = bid - NSH;
    int e = b >> 3;            // II/64 = 8 tiles per expert
    int i0 = (b & 7) * 64;
    int cnt = counts[e]; if(cnt == 0) return;
    int off = 0;
    for(int i=0;i<e;i++) off += counts[i];
    const float* Gp = Wgate + (size_t)e*HH*II + i0 + 4*m16;
    const float* Up = Wup   + (size_t)e*HH*II + i0 + 4*m16;
    for(int rt=0; rt*64<cnt; rt++){
      int nv = cnt - rt*64; if(nv > 64) nv = 64;
      const int* rows = token_list + e*TT + rt*64;
      int rr_ = r_lds < nv ? r_lds : nv-1;
      int rowg = rows[rr_];
      f32x4 ag[4]={zero,zero,zero,zero}, au[4]={zero,zero,zero,zero};
      const unsigned short* Asrc = xb + (size_t)rowg*HH + sseg*8;
      gemm64d<true>(Asrc, Gp, Up, II, HH/32, ag, au, Albuf, Bgbuf, Bubuf, tid);
      int mm = l&15, rr0 = w*16 + (l>>4)*4;
      #pragma unroll
      for(int c=0;c<4;c++){
        #pragma unroll
        for(int j=0;j<4;j++){
          int rr = rr0 + j;
          if(rr < nv){
            float g = ag[c][j], u = au[c][j];
            hbuf[(size_t)(off+rt*64+rr)*II + i0 + c*16 + mm] =
                f2bf(g*u/(1.f+__expf(-g)));
          }
        }
      }
    }
  }
}

// ---------------- phase 3: ALL down (shared + routed), 64x64 tiles ----------
__global__ __launch_bounds__(256, 2) void k_down_all(
    const unsigned short* __restrict__ Hsrc, const float* __restrict__ Wsd,
    const float* __restrict__ sig_gate,
    const unsigned short* __restrict__ hbuf, const float* __restrict__ Wdown,
    const int* __restrict__ token_list, const float* __restrict__ weight_list,
    const int* __restrict__ counts, float* __restrict__ out){
  __shared__ __align__(16) unsigned short Albuf[4*64*32];  // 16 KB
  __shared__ __align__(16) unsigned Bsbuf[2*16*64];        // 8 KB
  int tid = threadIdx.x, w = tid>>6, l = tid&63;
  int m16 = tid&15;
  const int r_lds = w*16 + (l>>2);
  const int sseg  = (l&3) ^ ((r_lds>>1)&3);
  int bid = blockIdx.x;
  f32x4 zero = {0.f,0.f,0.f,0.f};
  const int NSH = (TT/64)*(HH/64);   // 128

  if(bid < NSH){
    int n0 = (bid & 15) * 64;
    int r0 = (bid >> 4) * 64;
    f32x4 acc[4]={zero,zero,zero,zero};
    const unsigned short* Asrc = Hsrc + (size_t)(r0 + r_lds)*SS + sseg*8;
    const float* Bp = Wsd + n0 + 4*m16;
    gemm64d<false>(Asrc, Bp, Bp, HH, SS/32, acc, acc, Albuf, Bsbuf, Bsbuf, tid);
    int mm = l&15, rb = r0 + w*16 + (l>>4)*4;
    #pragma unroll
    for(int c=0;c<4;c++){
      #pragma unroll
      for(int j=0;j<4;j++){
        atomicAdd(&out[(size_t)(rb+j)*HH + n0 + c*16 + mm],
                  sig_gate[rb+j]*acc[c][j]);
      }
    }
  } else {
    int b = bid - NSH;
    int e = b >> 4;            // HH/64 = 16 tiles per expert
    int n0 = (b & 15) * 64;
    int cnt = counts[e]; if(cnt == 0) return;
    int off = 0;
    for(int i=0;i<e;i++) off += counts[i];
    const float* Bp = Wdown + (size_t)e*II*HH + n0 + 4*m16;
    for(int rt=0; rt*64<cnt; rt++){
      int nv = cnt - rt*64; if(nv > 64) nv = 64;
      int rr_ = r_lds < nv ? r_lds : nv-1;
      f32x4 acc[4]={zero,zero,zero,zero};
      const unsigned short* Asrc =
          hbuf + (size_t)(off+rt*64+rr_)*II + sseg*8;
      gemm64d<false>(Asrc, Bp, Bp, HH, II/32, acc, acc, Albuf, Bsbuf, Bsbuf, tid);
      int mm = l&15, rr0 = w*16 + (l>>4)*4;
      #pragma unroll
      for(int c=0;c<4;c++){
        #pragma unroll
        for(int j=0;j<4;j++){
          int rr = rr0 + j;
          if(rr < nv){
            int t = token_list[e*TT + rt*64 + rr];
            float wt = weight_list[e*TT + rt*64 + rr];
            atomicAdd(&out[(size_t)t*HH + n0 + c*16 + mm], wt*acc[c][j]);
          }
        }
      }
    }
  }
}

extern "C" void kernel_launch(void* const* d_in, const int* in_sizes, int n_in,
                              void* d_out, int out_size, void* d_ws, size_t ws_size,
                              hipStream_t stream) {
  const float* x     = (const float*)d_in[0];
  const float* Wg    = (const float*)d_in[1];
  const float* Wgate = (const float*)d_in[2];
  const float* Wup   = (const float*)d_in[3];
  const float* Wdown = (const float*)d_in[4];
  const float* Wsg   = (const float*)d_in[5];
  const float* Wsu   = (const float*)d_in[6];
  const float* Wsd   = (const float*)d_in[7];
  float* out = (float*)d_out;

  char* ws = (char*)d_ws;
  unsigned short* xb   = (unsigned short*)ws; ws += (size_t)TT*HH*2;
  unsigned short* Hs   = (unsigned short*)ws; ws += (size_t)TT*SS*2;
  unsigned short* hbuf = (unsigned short*)ws; ws += (size_t)(TT*KK+64)*II*2;
  int*   token_list  = (int*)ws;   ws += (size_t)EE*TT*4;
  float* weight_list = (float*)ws; ws += (size_t)EE*TT*4;
  int*   topk_idx    = (int*)ws;   ws += (size_t)TT*KK*4;
  float* topk_wq     = (float*)ws; ws += (size_t)TT*KK*4;
  int*   counts      = (int*)ws;   ws += 128;
  float* sig_gate    = (float*)ws; ws += (size_t)TT*4;

  hipMemsetAsync(d_out, 0, (size_t)TT*HH*4, stream);
  k_router<<<TT, 64, 0, stream>>>(x, Wg, xb, topk_idx, topk_wq, sig_gate);
  k_build<<<EE, 64, 0, stream>>>(topk_idx, topk_wq, token_list, weight_list, counts);
  k_gateup_all<<<(TT/64)*(SS/64) + EE*(II/64), 256, 0, stream>>>(
      xb, Wsg, Wsu, Hs, Wgate, Wup, token_list, counts, hbuf);
  k_down_all<<<(TT/64)*(HH/64) + EE*(HH/64), 256, 0, stream>>>(
      Hs, Wsd, sig_gate, hbuf, Wdown, token_list, weight_list, counts, out);
}